// Round 10
// baseline (1040.084 us; speedup 1.0000x reference)
//
#include <hip/hip_runtime.h>
#include <cstdint>

typedef _Float16 f16x2 __attribute__((ext_vector_type(2)));

// Clamp-free fast activations: gate pre-activations here are |x| <~ 15.
__device__ __forceinline__ float fsig(float x) {
  return __fdividef(1.f, 1.f + __expf(-x));
}
__device__ __forceinline__ float ftanh_(float x) {
  return fmaf(2.f, fsig(x + x), -1.f);
}
__device__ __forceinline__ int packf16(float a, float b) {
  f16x2 p; p.x = (_Float16)a; p.y = (_Float16)b;
  return __builtin_bit_cast(int, p);
}
__device__ __forceinline__ float dot2(int w, int h, float acc) {
  return __builtin_amdgcn_fdot2(__builtin_bit_cast(f16x2, w),
                                __builtin_bit_cast(f16x2, h), acc, false);
}
// Quad-lane permute at VALU speed (DPP), replacing LDS-pipe ds_swizzle.
template <int CTRL>
__device__ __forceinline__ float qp(float v) {
  return __int_as_float(__builtin_amdgcn_update_dpp(
      0, __float_as_int(v), CTRL, 0xF, 0xF, true));
}
#define QP_X1 0xB1  // quad_perm [1,0,3,2]
#define QP_X2 0x4E  // quad_perm [2,3,0,1]

// ---------------------------------------------------------------------------
// Layer 1: unchanged from R9 (~120 us) to isolate the lstm2 experiment.
// ---------------------------------------------------------------------------
__global__ __launch_bounds__(256, 2) void lstm1_kernel(
    const float* __restrict__ x, const float* __restrict__ Wih,
    const float* __restrict__ Whh, const float* __restrict__ bih,
    const float* __restrict__ bhh, int4* __restrict__ h1out) {
  const int n = blockIdx.x * 256 + threadIdx.x;  // chain id = b*S + s

  int whh2[128];  // whh2[r*4+j] = (Whh[r][2j], Whh[r][2j+1])
#pragma unroll
  for (int r = 0; r < 32; ++r) {
#pragma unroll
    for (int j = 0; j < 4; ++j) {
      float2 v = ((const float2*)(Whh + r * 8))[j];
      whh2[r * 4 + j] = packf16(v.x, v.y);
    }
  }
  int wxb[32];  // (Wih[r], bih[r]+bhh[r]); dotted with (x_t, 1)
#pragma unroll
  for (int r = 0; r < 32; ++r) wxb[r] = packf16(Wih[r], bih[r] + bhh[r]);

#pragma unroll
  for (int i = 0; i < 128; i += 8)
    asm volatile("" : "+v"(whh2[i]), "+v"(whh2[i + 1]), "+v"(whh2[i + 2]),
                      "+v"(whh2[i + 3]), "+v"(whh2[i + 4]), "+v"(whh2[i + 5]),
                      "+v"(whh2[i + 6]), "+v"(whh2[i + 7]));
#pragma unroll
  for (int i = 0; i < 32; i += 8)
    asm volatile("" : "+v"(wxb[i]), "+v"(wxb[i + 1]), "+v"(wxb[i + 2]),
                      "+v"(wxb[i + 3]), "+v"(wxb[i + 4]), "+v"(wxb[i + 5]),
                      "+v"(wxb[i + 6]), "+v"(wxb[i + 7]));

  const float* __restrict__ xp = x + (size_t)n * 16;
  float c[8];
  int h2[4];
#pragma unroll
  for (int k = 0; k < 8; ++k) c[k] = 0.f;
#pragma unroll
  for (int j = 0; j < 4; ++j) h2[j] = 0;

  float xv = xp[0];
#pragma unroll 1
  for (int t = 0; t < 16; ++t) {
    float xn = xp[(t + 1) & 15];
    const int xt1 = packf16(xv, 1.f);
    float hn[8];
#pragma unroll
    for (int k = 0; k < 8; ++k) {
      float acc[4];
#pragma unroll
      for (int gi = 0; gi < 4; ++gi) {
        const int r = gi * 8 + k;
        float a = dot2(wxb[r], xt1, 0.f);
        a = dot2(whh2[r * 4 + 0], h2[0], a);
        a = dot2(whh2[r * 4 + 1], h2[1], a);
        a = dot2(whh2[r * 4 + 2], h2[2], a);
        a = dot2(whh2[r * 4 + 3], h2[3], a);
        acc[gi] = a;
      }
      float iv = fsig(acc[0]), fv = fsig(acc[1]);
      float gv = ftanh_(acc[2]), ov = fsig(acc[3]);
      c[k] = fmaf(fv, c[k], iv * gv);
      hn[k] = ov * ftanh_(c[k]);
    }
#pragma unroll
    for (int j = 0; j < 4; ++j) h2[j] = packf16(hn[2 * j], hn[2 * j + 1]);
    xv = xn;
  }
  int4 o;
  o.x = h2[0]; o.y = h2[1]; o.z = h2[2]; o.w = h2[3];
  h1out[n] = o;
}

// ---------------------------------------------------------------------------
// Pack kernel: pre-packs lstm2's weights into thread-ordered f16 pairs so
// lstm2 can load them with VOLATILE loads (non-rematerializable -> the
// compiler cannot sink them back into the K-loop, the R4..R9 disease).
// ---------------------------------------------------------------------------
__global__ __launch_bounds__(64) void pack_kernel(
    const float* __restrict__ Wih, const float* __restrict__ Whh,
    const float* __restrict__ bih, const float* __restrict__ bhh,
    int* __restrict__ wpack, int* __restrict__ xwpack,
    float* __restrict__ bpack) {
  const int t = blockIdx.x * 64 + threadIdx.x;  // 0..511
  const int m = t >> 2, q = t & 3;
#pragma unroll
  for (int g = 0; g < 4; ++g) {
    const float* src = Whh + (size_t)(g * 128 + m) * 128 + q * 32;
#pragma unroll
    for (int j = 0; j < 16; ++j)
      wpack[t * 64 + g * 16 + j] = packf16(src[2 * j], src[2 * j + 1]);
    const float* xi = Wih + (size_t)(g * 128 + m) * 8;
#pragma unroll
    for (int j = 0; j < 4; ++j)
      xwpack[t * 16 + g * 4 + j] = packf16(xi[2 * j], xi[2 * j + 1]);
    bpack[t * 4 + g] = bih[g * 128 + m] + bhh[g * 128 + m];
  }
}

// ---------------------------------------------------------------------------
// Layer 2: B=256 recurrences -> 1 block (512 thr, 8 waves) per CU.
// Quad K-split with COMMITTEE reduce: thread (m=t>>2, q=t&3) holds K-quarter
// q of all four gate rows of index m (64 half2, VOLATILE-loaded pre-packed ->
// guaranteed VGPR-resident) and a quarter of h. All-reduce across the quad
// via DPP quad_perm butterflies (VALU pipe, no LDS, no selects); every quad
// thread computes all 4 gate activations + (c,h) itself — no gather. LDS
// pipe per step/CU: 1 ds_write_b16 x128 + 32 ds_read_b128 only.
// ---------------------------------------------------------------------------
__global__ __launch_bounds__(512, 2) void lstm2_kernel(
    const int4* __restrict__ h1, const int* __restrict__ wpack,
    const int* __restrict__ xwpack, const float* __restrict__ bpack,
    const float* __restrict__ Wd1, const float* __restrict__ bd1,
    const float* __restrict__ Wd2, const float* __restrict__ bd2,
    float* __restrict__ out) {
  __shared__ __align__(16) _Float16 sH[2][128];  // 512 B double-buffered h
  const int b = blockIdx.x;
  const int t = threadIdx.x;
  const int m = t >> 2;  // hidden index
  const int q = t & 3;   // K-quarter

  // volatile loads: cannot be rematerialized/sunk -> must stay in VGPRs
  int w[64];
  {
    const volatile int* wp = wpack + t * 64;
#pragma unroll
    for (int i = 0; i < 64; ++i) w[i] = wp[i];
  }
  int xw[16];
  {
    const volatile int* xp = xwpack + t * 16;
#pragma unroll
    for (int i = 0; i < 16; ++i) xw[i] = xp[i];
  }
  float bias[4];
  {
    const volatile float* bp = bpack + t * 4;
#pragma unroll
    for (int i = 0; i < 4; ++i) bias[i] = bp[i];
  }

  int hq[16];  // this thread's h-quarter (32 f16)
#pragma unroll
  for (int i = 0; i < 16; ++i) hq[i] = 0;
  float c = 0.f;  // cell state for index m (replicated across the quad)

  const int4* __restrict__ xq = h1 + (size_t)b * 1024;  // 8 f16 per step
  int4 xc = xq[0];  // uniform -> s_load

#pragma unroll 1
  for (int ts = 0; ts < 1024; ++ts) {
    int4 xn = xq[(ts + 1) & 1023];  // prefetch (wraps harmlessly)

    // x-part + bias for ALL 4 gates (committee)
    float A0 = bias[0], A1 = bias[1], A2 = bias[2], A3 = bias[3];
    A0 = dot2(xw[0], xc.x, A0);  A0 = dot2(xw[1], xc.y, A0);
    A0 = dot2(xw[2], xc.z, A0);  A0 = dot2(xw[3], xc.w, A0);
    A1 = dot2(xw[4], xc.x, A1);  A1 = dot2(xw[5], xc.y, A1);
    A1 = dot2(xw[6], xc.z, A1);  A1 = dot2(xw[7], xc.w, A1);
    A2 = dot2(xw[8], xc.x, A2);  A2 = dot2(xw[9], xc.y, A2);
    A2 = dot2(xw[10], xc.z, A2); A2 = dot2(xw[11], xc.w, A2);
    A3 = dot2(xw[12], xc.x, A3); A3 = dot2(xw[13], xc.y, A3);
    A3 = dot2(xw[14], xc.z, A3); A3 = dot2(xw[15], xc.w, A3);

    // quarter-dots of all 4 gate rows (64 dot2, 4 independent chains)
    float R0 = 0.f, R1 = 0.f, R2 = 0.f, R3 = 0.f;
#pragma unroll
    for (int j = 0; j < 16; ++j) {
      R0 = dot2(w[j], hq[j], R0);
      R1 = dot2(w[16 + j], hq[j], R1);
      R2 = dot2(w[32 + j], hq[j], R2);
      R3 = dot2(w[48 + j], hq[j], R3);
    }
    // committee all-reduce across the quad: DPP butterflies (VALU speed)
    R0 += qp<QP_X1>(R0); R0 += qp<QP_X2>(R0);
    R1 += qp<QP_X1>(R1); R1 += qp<QP_X2>(R1);
    R2 += qp<QP_X1>(R2); R2 += qp<QP_X2>(R2);
    R3 += qp<QP_X1>(R3); R3 += qp<QP_X2>(R3);

    // every quad thread computes all gates + state (no gather needed)
    float iv = fsig(A0 + R0);
    float fv = fsig(A1 + R1);
    float gv = ftanh_(A2 + R2);
    float ov = fsig(A3 + R3);
    c = fmaf(fv, c, iv * gv);
    float hx = ov * ftanh_(c);
    if (q == 0) sH[ts & 1][m] = (_Float16)hx;  // one writer per index
    __syncthreads();                           // the only barrier per step

    {  // refresh this thread's h-quarter: 4 x ds_read_b128 (broadcast groups)
      const int4* src = (const int4*)(&sH[ts & 1][q * 32]);
      int4 A = src[0], B = src[1], C = src[2], D = src[3];
      hq[0] = A.x;  hq[1] = A.y;  hq[2] = A.z;  hq[3] = A.w;
      hq[4] = B.x;  hq[5] = B.y;  hq[6] = B.z;  hq[7] = B.w;
      hq[8] = C.x;  hq[9] = C.y;  hq[10] = C.z; hq[11] = C.w;
      hq[12] = D.x; hq[13] = D.y; hq[14] = D.z; hq[15] = D.w;
    }
    xc = xn;
  }

  // Epilogue: out[b] = (h @ Wd1.T + bd1) @ Wd2.T + bd2; h_T is in sH[1].
  if (t < 64) {
    float a = bd1[t];
#pragma unroll
    for (int k = 0; k < 128; ++k)
      a = fmaf(Wd1[t * 128 + k], (float)sH[1][k], a);
    float v = a * Wd2[t];
#pragma unroll
    for (int off = 32; off > 0; off >>= 1) v += __shfl_down(v, off);
    if (t == 0) out[b] = v + bd2[0];
  }
}

extern "C" void kernel_launch(void* const* d_in, const int* in_sizes, int n_in,
                              void* d_out, int out_size, void* d_ws, size_t ws_size,
                              hipStream_t stream) {
  const float* x    = (const float*)d_in[0];
  // d_in[1] is the unused python scalar `data`
  const float* Wih1 = (const float*)d_in[2];
  const float* Whh1 = (const float*)d_in[3];
  const float* bih1 = (const float*)d_in[4];
  const float* bhh1 = (const float*)d_in[5];
  const float* Wih2 = (const float*)d_in[6];
  const float* Whh2 = (const float*)d_in[7];
  const float* bih2 = (const float*)d_in[8];
  const float* bhh2 = (const float*)d_in[9];
  const float* W1   = (const float*)d_in[10];
  const float* b1   = (const float*)d_in[11];
  const float* W2   = (const float*)d_in[12];
  const float* b2   = (const float*)d_in[13];
  float* out = (float*)d_out;

  // workspace layout
  char* ws = (char*)d_ws;
  int4*  h1     = (int4*)ws;                       // 4 MB
  int*   wpack  = (int*)(ws + (4 << 20));          // 512*64*4  = 128 KB
  int*   xwpack = (int*)(ws + (4 << 20) + (128 << 10));  // 32 KB
  float* bpack  = (float*)(ws + (4 << 20) + (160 << 10)); // 8 KB

  lstm1_kernel<<<1024, 256, 0, stream>>>(x, Wih1, Whh1, bih1, bhh1, h1);
  pack_kernel<<<8, 64, 0, stream>>>(Wih2, Whh2, bih2, bhh2,
                                    wpack, xwpack, bpack);
  lstm2_kernel<<<256, 512, 0, stream>>>(h1, wpack, xwpack, bpack,
                                        W1, b1, W2, b2, out);
}